// Round 1
// baseline (790.191 us; speedup 1.0000x reference)
//
#include <hip/hip_runtime.h>

#define Bv 1024
#define Ev 64
#define NOv 512
#define L2E  1.44269504088896340736f
#define L2E2 2.88539008177792681472f

typedef _Float16 h8 __attribute__((ext_vector_type(8)));
typedef float f32x4 __attribute__((ext_vector_type(4)));
typedef int i32x8 __attribute__((ext_vector_type(8)));

#define LDH8 272   // fp8 h/rh LDS row stride (bytes); 4 rows only (batch rows)
#define LDA1 264   // a1 fp16 LDS row stride (halves); 4 rows only
#define LDX  48    // x fp16 LDS row stride (halves); 4 rows only

#define MF16(a,b,c) __builtin_amdgcn_mfma_f32_16x16x32_f16((a),(b),(c),0,0,0)
#define MFS(a,b,c) __builtin_amdgcn_mfma_scale_f32_16x16x128_f8f6f4((a),(b),(c),0,0,0,0x7F7F7F7F,0,0x7F7F7F7F)

__device__ __forceinline__ float rcpf(float x) {
    float r; asm("v_rcp_f32 %0, %1" : "=v"(r) : "v"(x)); return r;
}
__device__ __forceinline__ float ex2(float x) {
    float r; asm("v_exp_f32 %0, %1" : "=v"(r) : "v"(x)); return r;
}
__device__ __forceinline__ float sig2(float y) { return rcpf(1.0f + ex2(-y)); }
__device__ __forceinline__ float tanh2(float y) { return fmaf(2.0f, sig2(y), -1.0f); }
__device__ __forceinline__ int pk4_fp8(float a, float b, float c, float d) {
    int p = __builtin_amdgcn_cvt_pk_fp8_f32(a, b, 0, false);
    p = __builtin_amdgcn_cvt_pk_fp8_f32(c, d, p, true);
    return p;
}

// Pack row-major (256 x ncols) fp32 matrix into fp8 fragments for 16x16x128 scaled MFMA
__global__ void pack_frag8w(const float* __restrict__ src, int4* __restrict__ dst,
                            int ntiles, int ncols, float scale) {
    int idx = blockIdx.x * 256 + threadIdx.x;
    int total = ntiles * 2 * 64;
    if (idx >= total) return;
    int lane = idx & 63;
    int kh = (idx >> 6) & 1;
    int ct = idx >> 7;
    int k0 = kh * 128 + (lane >> 4) * 32;
    int n = ct * 16 + (lane & 15);
    int w[8];
    #pragma unroll
    for (int q = 0; q < 8; ++q) {
        float s[4];
        #pragma unroll
        for (int j = 0; j < 4; ++j)
            s[j] = (n < ncols) ? scale * src[(k0 + q * 4 + j) * ncols + n] : 0.f;
        w[q] = pk4_fp8(s[0], s[1], s[2], s[3]);
    }
    dst[idx * 2]     = make_int4(w[0], w[1], w[2], w[3]);
    dst[idx * 2 + 1] = make_int4(w[4], w[5], w[6], w[7]);
}

__global__ void pack_frag16(const float* __restrict__ src, _Float16* __restrict__ dst,
                            int KS, int ntiles, int ncols, float scale) {
    int idx = blockIdx.x * 256 + threadIdx.x;
    int total = ntiles * KS * 64;
    if (idx >= total) return;
    int lane = idx & 63;
    int ks = (idx >> 6) % KS;
    int ct = (idx >> 6) / KS;
    int k0 = ks * 32 + (lane >> 4) * 8;
    int n = ct * 16 + (lane & 15);
    h8 v;
    #pragma unroll
    for (int j = 0; j < 8; ++j)
        v[j] = (n < ncols) ? (_Float16)(scale * src[(k0 + j) * ncols + n]) : (_Float16)0.f;
    ((h8*)dst)[idx] = v;
}

__global__ void inv_init(int* __restrict__ inv) {
    int i = blockIdx.x * blockDim.x + threadIdx.x;
    if (i < Ev * Bv) inv[i] = -1;
}
__global__ void inv_scatter(const int* __restrict__ bidx, int* __restrict__ inv) {
    int i = blockIdx.x * blockDim.x + threadIdx.x;
    if (i < Ev * NOv) {
        int e = i >> 9;
        int o = i & (NOv - 1);
        inv[e * Bv + bidx[i]] = o;
    }
}
__global__ void gather_x(const float* __restrict__ X, const int* __restrict__ bidx,
                         _Float16* __restrict__ Xg) {
    int i = blockIdx.x * 256 + threadIdx.x;
    if (i >= Ev * NOv * 32) return;
    int q = i & 31, o = (i >> 5) & (NOv - 1), e = i >> 14;
    int b = bidx[e * NOv + o];
    Xg[(e * Bv + b) * 32 + q] = (_Float16)X[i];
}
__global__ void gather_t(const float* __restrict__ X, const float* __restrict__ M,
                         const int* __restrict__ bidx,
                         float* __restrict__ Tx, float* __restrict__ Tm) {
    int i = blockIdx.x * 256 + threadIdx.x;
    if (i >= Ev * NOv * 16) return;
    int m = i & 15, o = (i >> 4) & (NOv - 1), e = i >> 13;
    int b = bidx[e * NOv + o];
    int d = (e * Bv + b) * 16 + m;
    if (m < 15) {
        Tx[d] = X[((e * NOv + o) * 16 + 1 + m) * 2];
        Tm[d] = M[(e * NOv + o) * 16 + 1 + m];
    } else {
        Tx[d] = 1.f;
        Tm[d] = 0.f;
    }
}

// 256 blocks x 512 threads (8 waves, 2/SIMD). Block owns batch rows [4b,4b+4).
// Wave w owns hidden cols [32w,32w+32) as TWO 16-col MFMA tiles sharing one
// B-operand read (halves redundant LDS traffic vs 16x1-tile). Everything stays
// in MFMA C-layout: lane (l16,lg) holds batch row (l16&3) x 4 cols per tile;
// rows l16>=4 of C are replicas (B columns fed by broadcast of rows 0..3),
// masked by the obsi guard. No ds_bpermute gathers anywhere. Euler weights
// (12 x i32x8) and euler biases (6 x f32x4) pinned in registers; 2 waves/SIMD
// allows 256 VGPR -> no scratch spills (old 64-VGPR cap spilled ~27MB/launch).
__global__ __launch_bounds__(512, 2) void gruode_main(
    const _Float16* __restrict__ Xg, const float* __restrict__ Tx, const float* __restrict__ Tm,
    const float* __restrict__ dtp,
    const float* __restrict__ br, const float* __restrict__ bz, const float* __restrict__ bh,
    const float* __restrict__ bxr, const float* __restrict__ bxz, const float* __restrict__ bxn,
    const float* __restrict__ bhr, const float* __restrict__ bhz, const float* __restrict__ bhn,
    const float* __restrict__ b1, const float* __restrict__ b2,
    const i32x8* __restrict__ WrQ, const i32x8* __restrict__ WzQ, const i32x8* __restrict__ WhQ,
    const i32x8* __restrict__ UhrQ, const i32x8* __restrict__ UhzQ, const i32x8* __restrict__ UhnQ,
    const i32x8* __restrict__ W1Q,
    const h8* __restrict__ WxrH, const h8* __restrict__ WxzH, const h8* __restrict__ WxnH,
    const h8* __restrict__ W2H,
    const int* __restrict__ inv, double* __restrict__ partials)
{
    __shared__ __align__(16) char     h8s[4 * LDH8];
    __shared__ __align__(16) char     rh8s[4 * LDH8];
    __shared__ __align__(16) _Float16 a1s[4 * LDA1];
    __shared__ __align__(16) _Float16 x16s[4 * LDX];
    __shared__ __align__(16) float    bias_s[5][256];
    __shared__ __align__(16) float    b2s[16];
    __shared__ int    obsi_s[16];
    __shared__ double wred[8][4];

    const int tid  = threadIdx.x;
    const int lane = tid & 63;
    const int wid  = tid >> 6;       // 0..7
    const int l16  = lane & 15;      // C row (batch row replica index)
    const int lg   = lane >> 4;
    const int rrow = l16 & 3;        // valid batch row for B-operand broadcast reads
    const int c0   = wid * 32 + lg * 4;   // tile0 col base; tile1 = c0+16
    const int row0 = blockIdx.x * 4;
    const float dtv = dtp[0];

    if (tid < 256) {
        bias_s[0][tid] = (bxr[tid] + bhr[tid]) * L2E;
        bias_s[1][tid] = (bxz[tid] + bhz[tid]) * L2E;
        bias_s[2][tid] = bxn[tid] * L2E2;
    } else {
        int t = tid - 256;
        bias_s[3][t] = bhn[t] * L2E2;
        bias_s[4][t] = b1[t];
    }
    if (tid < 16) b2s[tid] = (tid < 15) ? b2[tid] : 0.f;
    if (tid < LDH8) {   // 4*LDH8 bytes = LDH8 ints each
        ((int*)h8s)[tid] = 0;
        ((int*)rh8s)[tid] = 0;
    }

    // pinned euler weight^T fp8 slices: 2 tiles x 3 mats x 2 K-halves = 12 x i32x8
    const int t0 = (wid * 2 + 0) * 2;
    const int t1 = (wid * 2 + 1) * 2;
    i32x8 wr00 = WrQ[(t0+0)*64+lane], wr01 = WrQ[(t0+1)*64+lane];
    i32x8 wr10 = WrQ[(t1+0)*64+lane], wr11 = WrQ[(t1+1)*64+lane];
    i32x8 wz00 = WzQ[(t0+0)*64+lane], wz01 = WzQ[(t0+1)*64+lane];
    i32x8 wz10 = WzQ[(t1+0)*64+lane], wz11 = WzQ[(t1+1)*64+lane];
    i32x8 wh00 = WhQ[(t0+0)*64+lane], wh01 = WhQ[(t0+1)*64+lane];
    i32x8 wh10 = WhQ[(t1+0)*64+lane], wh11 = WhQ[(t1+1)*64+lane];

    // pinned euler biases (pre-scaled for ex2-based activations)
    f32x4 bR0 = L2E  * (*(const f32x4*)&br[c0]);
    f32x4 bR1 = L2E  * (*(const f32x4*)&br[c0 + 16]);
    f32x4 bZ0 = L2E  * (*(const f32x4*)&bz[c0]);
    f32x4 bZ1 = L2E  * (*(const f32x4*)&bz[c0 + 16]);
    f32x4 bU0 = L2E2 * (*(const f32x4*)&bh[c0]);
    f32x4 bU1 = L2E2 * (*(const f32x4*)&bh[c0 + 16]);

    float hs0[4] = {0.f, 0.f, 0.f, 0.f};   // fp32 h master, C layout (row rrow, cols c0..c0+3)
    float hs1[4] = {0.f, 0.f, 0.f, 0.f};   // tile1: cols c0+16..c0+19
    double am0 = 0.0, am1 = 0.0, am2 = 0.0, am3 = 0.0;
    __syncthreads();

    for (int e = 0; e < Ev; ++e) {
        // event-start prefetch
        if (tid < 16) obsi_s[tid] = (tid < 4) ? inv[e * Bv + row0 + tid] : -1;
        if (tid < 128) {
            int row = tid >> 5, q = tid & 31;
            x16s[row * LDX + q] = Xg[(e * Bv + row0 + row) * 32 + q];
        }
        float4 txv = {0.f,0.f,0.f,0.f}, tmv = {0.f,0.f,0.f,0.f};
        if (wid == 0) {
            int gr = row0 + l16; if (gr > Bv - 1) gr = Bv - 1;
            txv = *(const float4*)&Tx[(e * Bv + gr) * 16 + lg * 4];
            tmv = *(const float4*)&Tm[(e * Bv + gr) * 16 + lg * 4];
        }

        // ---------------- 4 Euler steps ----------------
        for (int s = 0; s < 4; ++s) {
            i32x8 hb0 = *(const i32x8*)&h8s[rrow * LDH8 + lg * 32];
            i32x8 hb1 = *(const i32x8*)&h8s[rrow * LDH8 + 128 + lg * 32];
            f32x4 aR0 = bR0, aR1 = bR1, aZ0 = bZ0, aZ1 = bZ1;
            aR0 = MFS(wr00, hb0, aR0); aR0 = MFS(wr01, hb1, aR0);
            aZ0 = MFS(wz00, hb0, aZ0); aZ0 = MFS(wz01, hb1, aZ0);
            aR1 = MFS(wr10, hb0, aR1); aR1 = MFS(wr11, hb1, aR1);
            aZ1 = MFS(wz10, hb0, aZ1); aZ1 = MFS(wz11, hb1, aZ1);
            float zs0[4], zs1[4], rh0[4], rh1[4];
            #pragma unroll
            for (int r = 0; r < 4; ++r) {
                rh0[r] = sig2(aR0[r]) * hs0[r]; zs0[r] = sig2(aZ0[r]);
                rh1[r] = sig2(aR1[r]) * hs1[r]; zs1[r] = sig2(aZ1[r]);
            }
            if (l16 < 4) {
                *(int*)&rh8s[l16 * LDH8 + c0]      = pk4_fp8(rh0[0], rh0[1], rh0[2], rh0[3]);
                *(int*)&rh8s[l16 * LDH8 + c0 + 16] = pk4_fp8(rh1[0], rh1[1], rh1[2], rh1[3]);
            }
            __syncthreads();
            i32x8 rb0 = *(const i32x8*)&rh8s[rrow * LDH8 + lg * 32];
            i32x8 rb1 = *(const i32x8*)&rh8s[rrow * LDH8 + 128 + lg * 32];
            f32x4 aU0 = bU0, aU1 = bU1;
            aU0 = MFS(wh00, rb0, aU0); aU0 = MFS(wh01, rb1, aU0);
            aU1 = MFS(wh10, rb0, aU1); aU1 = MFS(wh11, rb1, aU1);
            #pragma unroll
            for (int r = 0; r < 4; ++r) {
                float u0 = tanh2(aU0[r]);
                float u1 = tanh2(aU1[r]);
                hs0[r] = hs0[r] + dtv * (1.f - zs0[r]) * (u0 - hs0[r]);
                hs1[r] = hs1[r] + dtv * (1.f - zs1[r]) * (u1 - hs1[r]);
            }
            if (l16 < 4) {
                *(int*)&h8s[l16 * LDH8 + c0]      = pk4_fp8(hs0[0], hs0[1], hs0[2], hs0[3]);
                *(int*)&h8s[l16 * LDH8 + c0 + 16] = pk4_fp8(hs1[0], hs1[1], hs1[2], hs1[3]);
            }
            __syncthreads();
        }

        // ---------------- event extras (all C-layout, no gathers) ----------------
        i32x8 hb0 = *(const i32x8*)&h8s[rrow * LDH8 + lg * 32];
        i32x8 hb1 = *(const i32x8*)&h8s[rrow * LDH8 + 128 + lg * 32];
        const int myobs = obsi_s[rrow];
        __syncthreads();   // all waves read h before pass3 rewrites it
        // pass1: nH (Uhn) + a1 (W1)
        f32x4 aN0 = *(const f32x4*)&bias_s[3][c0];
        f32x4 aN1 = *(const f32x4*)&bias_s[3][c0 + 16];
        {
            f32x4 aW0 = *(const f32x4*)&bias_s[4][c0];
            f32x4 aW1 = *(const f32x4*)&bias_s[4][c0 + 16];
            aN0 = MFS(UhnQ[(t0+0)*64+lane], hb0, aN0); aN0 = MFS(UhnQ[(t0+1)*64+lane], hb1, aN0);
            aN1 = MFS(UhnQ[(t1+0)*64+lane], hb0, aN1); aN1 = MFS(UhnQ[(t1+1)*64+lane], hb1, aN1);
            aW0 = MFS(W1Q[(t0+0)*64+lane], hb0, aW0);  aW0 = MFS(W1Q[(t0+1)*64+lane], hb1, aW0);
            aW1 = MFS(W1Q[(t1+0)*64+lane], hb0, aW1);  aW1 = MFS(W1Q[(t1+1)*64+lane], hb1, aW1);
            if (l16 < 4) {
                _Float16 a1v[4];
                #pragma unroll
                for (int r = 0; r < 4; ++r) a1v[r] = (_Float16)fmaxf(aW0[r], 0.f);
                *(long*)&a1s[l16 * LDA1 + c0] = *(const long*)a1v;
                #pragma unroll
                for (int r = 0; r < 4; ++r) a1v[r] = (_Float16)fmaxf(aW1[r], 0.f);
                *(long*)&a1s[l16 * LDA1 + c0 + 16] = *(const long*)a1v;
            }
        }
        h8 bx = *(const h8*)&x16s[rrow * LDX + lg * 8];
        // pass2: r gate
        float rg0[4], rg1[4];
        {
            f32x4 aG0 = *(const f32x4*)&bias_s[0][c0];
            f32x4 aG1 = *(const f32x4*)&bias_s[0][c0 + 16];
            aG0 = MFS(UhrQ[(t0+0)*64+lane], hb0, aG0); aG0 = MFS(UhrQ[(t0+1)*64+lane], hb1, aG0);
            aG1 = MFS(UhrQ[(t1+0)*64+lane], hb0, aG1); aG1 = MFS(UhrQ[(t1+1)*64+lane], hb1, aG1);
            aG0 = MF16(WxrH[(wid*2+0)*64+lane], bx, aG0);
            aG1 = MF16(WxrH[(wid*2+1)*64+lane], bx, aG1);
            #pragma unroll
            for (int r = 0; r < 4; ++r) { rg0[r] = sig2(aG0[r]); rg1[r] = sig2(aG1[r]); }
        }
        // pass3: z gate + nX -> h-new, commit (how[] is just hs - same layout)
        {
            f32x4 aG0 = *(const f32x4*)&bias_s[1][c0];
            f32x4 aG1 = *(const f32x4*)&bias_s[1][c0 + 16];
            aG0 = MFS(UhzQ[(t0+0)*64+lane], hb0, aG0); aG0 = MFS(UhzQ[(t0+1)*64+lane], hb1, aG0);
            aG1 = MFS(UhzQ[(t1+0)*64+lane], hb0, aG1); aG1 = MFS(UhzQ[(t1+1)*64+lane], hb1, aG1);
            aG0 = MF16(WxzH[(wid*2+0)*64+lane], bx, aG0);
            aG1 = MF16(WxzH[(wid*2+1)*64+lane], bx, aG1);
            f32x4 aNx0 = *(const f32x4*)&bias_s[2][c0];
            f32x4 aNx1 = *(const f32x4*)&bias_s[2][c0 + 16];
            aNx0 = MF16(WxnH[(wid*2+0)*64+lane], bx, aNx0);
            aNx1 = MF16(WxnH[(wid*2+1)*64+lane], bx, aNx1);
            #pragma unroll
            for (int r = 0; r < 4; ++r) {
                float zg = sig2(aG0[r]);
                float nv = tanh2(aNx0[r] + rg0[r] * aN0[r]);
                float hn = (1.f - zg) * nv + zg * hs0[r];
                if (myobs >= 0) hs0[r] = hn;
                zg = sig2(aG1[r]);
                nv = tanh2(aNx1[r] + rg1[r] * aN1[r]);
                hn = (1.f - zg) * nv + zg * hs1[r];
                if (myobs >= 0) hs1[r] = hn;
            }
            if (l16 < 4) {
                *(int*)&h8s[l16 * LDH8 + c0]      = pk4_fp8(hs0[0], hs0[1], hs0[2], hs0[3]);
                *(int*)&h8s[l16 * LDH8 + c0 + 16] = pk4_fp8(hs1[0], hs1[1], hs1[2], hs1[3]);
            }
        }
        __syncthreads();   // a1s + h8s updates visible
        // W2 GEMM + metrics: wave 0 only, overlaps other waves' next-event phase-1
        if (wid == 0) {
            f32x4 aP = *(const f32x4*)&b2s[lg * 4];
            #pragma unroll
            for (int ks = 0; ks < 8; ++ks) {
                h8 ba = *(const h8*)&a1s[(l16 & 3) * LDA1 + ks * 32 + lg * 8];
                aP = MF16(W2H[ks * 64 + lane], ba, aP);
            }
            if (obsi_s[l16] >= 0) {
                #pragma unroll
                for (int r = 0; r < 4; ++r) {
                    float p  = aP[r];
                    float xt = ((const float*)&txv)[r];
                    float mt = ((const float*)&tmv)[r];
                    float diff = xt - p;
                    am0 += (double)(diff * diff * mt);
                    am1 += (double)(fabsf(diff) * mt);
                    am2 += (double)(fabsf(diff) * rcpf(xt + 1e-8f) * mt);
                    am3 += (double)mt;
                }
            }
        }
    }

    __syncthreads();
    // deterministic metric reduction
    double v[4] = {am0, am1, am2, am3};
    #pragma unroll
    for (int m = 0; m < 4; ++m) {
        double t = v[m];
        for (int off = 32; off; off >>= 1) t += __shfl_down(t, off);
        if (lane == 0) wred[wid][m] = t;
    }
    __syncthreads();
    if (tid == 0) {
        for (int m = 0; m < 4; ++m) {
            double t = 0.0;
            for (int w = 0; w < 8; ++w) t += wred[w][m];
            partials[blockIdx.x * 4 + m] = t;
        }
    }
}

__global__ void finalize_k(const double* __restrict__ partials, float* __restrict__ out) {
    __shared__ double sd[4][4];
    int t = threadIdx.x;   // 256
    int l = t & 63, w = t >> 6;
    double v0 = partials[t * 4 + 0];
    double v1 = partials[t * 4 + 1];
    double v2 = partials[t * 4 + 2];
    double v3 = partials[t * 4 + 3];
    for (int off = 32; off; off >>= 1) {
        v0 += __shfl_down(v0, off);
        v1 += __shfl_down(v1, off);
        v2 += __shfl_down(v2, off);
        v3 += __shfl_down(v3, off);
    }
    if (l == 0) { sd[w][0] = v0; sd[w][1] = v1; sd[w][2] = v2; sd[w][3] = v3; }
    __syncthreads();
    if (t == 0) {
        double r0 = 0, r1 = 0, r2 = 0, r3 = 0;
        for (int i = 0; i < 4; ++i) { r0 += sd[i][0]; r1 += sd[i][1]; r2 += sd[i][2]; r3 += sd[i][3]; }
        out[0] = (float)(r0 / r3);
        out[1] = (float)(r1 / r3);
        out[2] = (float)(r2 / r3);
    }
}

extern "C" void kernel_launch(void* const* d_in, const int* in_sizes, int n_in,
                              void* d_out, int out_size, void* d_ws, size_t ws_size,
                              hipStream_t stream) {
    const float* X   = (const float*)d_in[0];
    const float* M   = (const float*)d_in[1];
    const int*  bidx = (const int*)d_in[2];
    const float* dtp = (const float*)d_in[3];
    const float* Wr  = (const float*)d_in[4];
    const float* brr = (const float*)d_in[5];
    const float* Wz  = (const float*)d_in[6];
    const float* bzz = (const float*)d_in[7];
    const float* Wh  = (const float*)d_in[8];
    const float* bhh = (const float*)d_in[9];
    const float* Wxr = (const float*)d_in[10];
    const float* Wxz = (const float*)d_in[11];
    const float* Wxn = (const float*)d_in[12];
    const float* Uhr = (const float*)d_in[13];
    const float* Uhz = (const float*)d_in[14];
    const float* Uhn = (const float*)d_in[15];
    const float* bxr = (const float*)d_in[16];
    const float* bxz = (const float*)d_in[17];
    const float* bxn = (const float*)d_in[18];
    const float* bhr = (const float*)d_in[19];
    const float* bhz = (const float*)d_in[20];
    const float* bhn = (const float*)d_in[21];
    const float* W1  = (const float*)d_in[22];
    const float* b1  = (const float*)d_in[23];
    const float* W2  = (const float*)d_in[24];
    const float* b2  = (const float*)d_in[25];

    char* w = (char*)d_ws;
    i32x8* WrQ  = (i32x8*)(w + 0 * 65536);
    i32x8* WzQ  = (i32x8*)(w + 1 * 65536);
    i32x8* WhQ  = (i32x8*)(w + 2 * 65536);
    i32x8* UhrQ = (i32x8*)(w + 3 * 65536);
    i32x8* UhzQ = (i32x8*)(w + 4 * 65536);
    i32x8* UhnQ = (i32x8*)(w + 5 * 65536);
    i32x8* W1Q  = (i32x8*)(w + 6 * 65536);
    _Float16* WxrH = (_Float16*)(w + 458752);
    _Float16* WxzH = (_Float16*)(w + 475136);
    _Float16* WxnH = (_Float16*)(w + 491520);
    _Float16* W2H  = (_Float16*)(w + 507904);
    int* inv = (int*)(w + 516096);
    _Float16* Xg = (_Float16*)(w + 778240);
    float* Tx = (float*)(w + 4972544);
    float* Tm = (float*)(w + 9166848);
    double* partials = (double*)(w + 13361152);

    pack_frag8w<<<8, 256, 0, stream>>>(Wr,  (int4*)WrQ,  16, 256, L2E);
    pack_frag8w<<<8, 256, 0, stream>>>(Wz,  (int4*)WzQ,  16, 256, L2E);
    pack_frag8w<<<8, 256, 0, stream>>>(Wh,  (int4*)WhQ,  16, 256, L2E2);
    pack_frag8w<<<8, 256, 0, stream>>>(Uhr, (int4*)UhrQ, 16, 256, L2E);
    pack_frag8w<<<8, 256, 0, stream>>>(Uhz, (int4*)UhzQ, 16, 256, L2E);
    pack_frag8w<<<8, 256, 0, stream>>>(Uhn, (int4*)UhnQ, 16, 256, L2E2);
    pack_frag8w<<<8, 256, 0, stream>>>(W1,  (int4*)W1Q,  16, 256, 1.0f);
    pack_frag16<<<4, 256, 0, stream>>>(Wxr, WxrH, 1, 16, 256, L2E);
    pack_frag16<<<4, 256, 0, stream>>>(Wxz, WxzH, 1, 16, 256, L2E);
    pack_frag16<<<4, 256, 0, stream>>>(Wxn, WxnH, 1, 16, 256, L2E2);
    pack_frag16<<<2, 256, 0, stream>>>(W2,  W2H,  8, 1, 15, 1.0f);
    inv_init<<<256, 256, 0, stream>>>(inv);
    inv_scatter<<<128, 256, 0, stream>>>(bidx, inv);
    gather_x<<<4096, 256, 0, stream>>>(X, bidx, Xg);
    gather_t<<<2048, 256, 0, stream>>>(X, M, bidx, Tx, Tm);

    gruode_main<<<256, 512, 0, stream>>>(Xg, Tx, Tm, dtp,
        brr, bzz, bhh, bxr, bxz, bxn, bhr, bhz, bhn, b1, b2,
        WrQ, WzQ, WhQ, UhrQ, UhzQ, UhnQ, W1Q,
        (const h8*)WxrH, (const h8*)WxzH, (const h8*)WxnH, (const h8*)W2H,
        inv, partials);

    finalize_k<<<1, 256, 0, stream>>>(partials, (float*)d_out);
}